// Round 10
// baseline (242.609 us; speedup 1.0000x reference)
//
#include <hip/hip_runtime.h>
#include <math.h>

#define TT  34   // seq len
#define VV  14   // vocab
#define BLK 512  // 8 waves; block = 64 sequences x one 8-t chunk (uniform t per wave)

typedef float v2f __attribute__((ext_vector_type(2)));
typedef float v4f __attribute__((ext_vector_type(4)));

#if __has_builtin(__builtin_amdgcn_exp2f)
#define EXP2F(x) __builtin_amdgcn_exp2f(x)
#else
#define EXP2F(x) exp2f(x)
#endif
#if __has_builtin(__builtin_amdgcn_rcpf)
#define RCPF(x) __builtin_amdgcn_rcpf(x)
#else
#define RCPF(x) (1.0f/(x))
#endif

static __device__ __forceinline__ v2f fma2(v2f a, v2f b, v2f c) {
    return __builtin_elementwise_fma(a, b, c);   // -> v_pk_fma_f32 on gfx950
}
static __device__ __forceinline__ v2f bc2(float s) { v2f r; r.x = s; r.y = s; return r; }
#define SV2(v, a, b) __builtin_shufflevector((v), (v), (a), (b))
#define LD2(i) (*reinterpret_cast<const v2f*>(&wsm[(i)]))

// wsm layout (floats), all v2f read-bases even (8B-aligned):
//   0..35   owT[j*6+d]   = out_w[d*6+j]
//  36..41   ln2_g        42..47 ln2_b
//  48..59   w1p[d*2+i]   = ffn_w1[i*6+d], i in {0,1}
//  60..65   w1r[d]       = ffn_w1[12+d]
//  66..68   ffn_b1       69 pad
//  70..87   w2T[i*6+d]   = ffn_w2[d*3+i]
//  88..93   ffn_b2       94..95 pad
//  96..107  Gp[d*2+c]    = lnf_g[d]*head_w[c*6+d], c in {0,1}
// 108..113  G2[d]        = lnf_g[d]*head_w[12+d]
// 114..117  pad
// 118..120  eC[c]        = sum_d lnf_b[d]*head_w[c*6+d]
// 121      pad
// 122..163  MT[c*14+v]   = tok_emb[v*3+c]   (fused head rows)
// 164..205  tok_emb natural [v*3+c]
// 206..307  pos_enc natural [t*3+c]

// Chunk map (c = blockIdx.x % 5): c<4 -> t in [2+8c, 9+8c] (8 waves);
// c==4 -> t in {0,1} (2 waves; the SHORT trips get the partial chunk, so the
// 6 idle waves waste ~nothing). kv table built only up to the chunk's t_max.
// __launch_bounds__(512,4): 4 blocks x 8 waves = 32 waves/CU -> VGPR cap 64
// under the measured min-BLOCKS semantics (r6/r8/r9 decode); kernel needs ~30.
__global__ __launch_bounds__(BLK, 4) void addtx_fwd(
    const int*   __restrict__ idx,
    const float* __restrict__ tok_emb,
    const float* __restrict__ pos_enc,
    const float* __restrict__ q_w,
    const float* __restrict__ k_w,
    const float* __restrict__ v_w,
    const float* __restrict__ out_w,
    const float* __restrict__ ln1_g, const float* __restrict__ ln1_b,
    const float* __restrict__ ln2_g, const float* __restrict__ ln2_b,
    const float* __restrict__ lnf_g, const float* __restrict__ lnf_b,
    const float* __restrict__ ffn_w1, const float* __restrict__ ffn_b1,
    const float* __restrict__ ffn_w2, const float* __restrict__ ffn_b2,
    const float* __restrict__ head_w,
    float* __restrict__ out)
{
    // kv entry e=(pos,tok), pair-interleaved, k pre-scaled 1/sqrt(3)*log2e:
    //  f4[0]=(k0,k3,k1,k4)  f4[1]=(k2,k5,v0,v3)  f4[2]=(v1,v4,v2,v5)
    __shared__ v4f            kvs[TT * VV * 3];  // 22848 B
    __shared__ float          wsm[308];          //  1232 B
    __shared__ unsigned short ids16[35 * 64];    //  4480 B  [s][lane], id*48, +pad row

    const int tid = threadIdx.x;
    const int bid = blockIdx.x;
    const int c   = bid % 5;             // t-chunk (interleaved dispatch mixes lengths)
    const int sc  = bid / 5;             // sequence-chunk
    const int b0  = sc * 64;
    const int t_base = (c == 4) ? 0 : (2 + 8 * c);
    const int nt     = (c == 4) ? 2 : 8;
    const int nrow   = t_base + nt;      // kv rows needed = t_max + 1

    // ---------------- stage weights (transposed / pair-interleaved) ----------------
    if (tid < 308) {
        const int i = tid;
        float val = 0.0f;
        if (i < 36)       { const int j = i / 6, d = i - j * 6; val = out_w[d * 6 + j]; }
        else if (i < 42)  val = ln2_g[i - 36];
        else if (i < 48)  val = ln2_b[i - 42];
        else if (i < 60)  { const int k = i - 48, d = k >> 1, ii = k & 1; val = ffn_w1[ii * 6 + d]; }
        else if (i < 66)  val = ffn_w1[12 + (i - 60)];
        else if (i < 69)  val = ffn_b1[i - 66];
        else if (i < 70)  val = 0.0f;
        else if (i < 88)  { const int k = i - 70, ii = k / 6, d = k - ii * 6; val = ffn_w2[d * 3 + ii]; }
        else if (i < 94)  val = ffn_b2[i - 88];
        else if (i < 96)  val = 0.0f;
        else if (i < 108) { const int k = i - 96, d = k >> 1, cc = k & 1; val = lnf_g[d] * head_w[cc * 6 + d]; }
        else if (i < 114) { const int d = i - 108; val = lnf_g[d] * head_w[12 + d]; }
        else if (i < 118) val = 0.0f;
        else if (i < 121) { const int cc = i - 118; float s = 0.0f;
                            #pragma unroll
                            for (int d = 0; d < 6; ++d) s += lnf_b[d] * head_w[cc * 6 + d];
                            val = s; }
        else if (i < 122) val = 0.0f;
        else if (i < 164) { const int k = i - 122, cc = k / 14, v = k - cc * 14; val = tok_emb[v * 3 + cc]; }
        else if (i < 206) val = tok_emb[i - 164];
        else              val = pos_enc[i - 206];
        wsm[i] = val;
    }

    // ---------------- stage token ids: coalesced read, transposed u16 write ----------------
    // ids16[s][bl] = idx[(b0+bl)*34 + s] * 48 (byte offset into a kv row block).
    {
        const int gb = b0 * TT;
        for (int e = tid; e < 64 * TT; e += BLK) {
            const int v  = idx[gb + e];
            const int bl = e / TT, s = e - bl * TT;
            ids16[s * 64 + bl] = (unsigned short)(v * 48);
        }
        if (tid < 64) ids16[TT * 64 + tid] = 0;   // prefetch-safety row
    }

    // ---------------- build (pos,tok) -> k,v table, rows [0, nrow) ----------------
    const float rs3l = 0.57735026918962576f * 1.4426950408889634f; // 1/sqrt(3)*log2e
    for (int e = tid; e < nrow * VV; e += BLK) {
        const int pos = e / VV, id = e - pos * VV;
        float x[6];
        x[0] = tok_emb[id * 3 + 0]; x[1] = tok_emb[id * 3 + 1]; x[2] = tok_emb[id * 3 + 2];
        x[3] = pos_enc[pos * 3 + 0]; x[4] = pos_enc[pos * 3 + 1]; x[5] = pos_enc[pos * 3 + 2];
        float mu = (x[0] + x[1] + x[2] + x[3] + x[4] + x[5]) * (1.0f / 6.0f);
        float var = 0.0f;
        #pragma unroll
        for (int d = 0; d < 6; ++d) { float dd = x[d] - mu; var += dd * dd; }
        const float rstd = rsqrtf(var * (1.0f / 6.0f) + 1e-5f);
        float h[6];
        #pragma unroll
        for (int d = 0; d < 6; ++d) h[d] = (x[d] - mu) * rstd * ln1_g[d] + ln1_b[d];
        float kk[6], vvv[6];
        #pragma unroll
        for (int r = 0; r < 6; ++r) {
            kk[r]  = (h[3] * k_w[r * 3 + 0] + h[4] * k_w[r * 3 + 1] + h[5] * k_w[r * 3 + 2]) * rs3l;
            vvv[r] =  h[0] * v_w[r * 3 + 0] + h[1] * v_w[r * 3 + 1] + h[2] * v_w[r * 3 + 2];
        }
        v4f f0; f0.x = kk[0]; f0.y = kk[3]; f0.z = kk[1]; f0.w = kk[4];
        v4f f1; f1.x = kk[2]; f1.y = kk[5]; f1.z = vvv[0]; f1.w = vvv[3];
        v4f f2; f2.x = vvv[1]; f2.y = vvv[4]; f2.z = vvv[2]; f2.w = vvv[5];
        kvs[e * 3 + 0] = f0;
        kvs[e * 3 + 1] = f1;
        kvs[e * 3 + 2] = f2;
    }
    __syncthreads();     // the ONLY barrier; waves retire independently after this

    // ---------------- per-element work: wave w owns t = t_base + w (uniform) ----------------
    const int w = tid >> 6, lane = tid & 63;
    const int t = t_base + w;
    if (w >= nt) return;                 // c==4 idle waves exit (no barriers remain)
    const int b = b0 + lane;

    // own x (pre-LN residual) from LDS tables
    float x[6];
    const int tb3 = ((int)ids16[t * 64 + lane]) >> 4;   // id*3
    x[0] = wsm[164 + tb3]; x[1] = wsm[165 + tb3]; x[2] = wsm[166 + tb3];
    x[3] = wsm[206 + t * 3]; x[4] = wsm[207 + t * 3]; x[5] = wsm[208 + t * 3];

    // q
    float q[6];
    {
        float mu = (x[0] + x[1] + x[2] + x[3] + x[4] + x[5]) * (1.0f / 6.0f);
        float var = 0.0f;
        #pragma unroll
        for (int d = 0; d < 6; ++d) { float dd = x[d] - mu; var += dd * dd; }
        const float rstd = rsqrtf(var * (1.0f / 6.0f) + 1e-5f);
        const float h3 = (x[3] - mu) * rstd * ln1_g[3] + ln1_b[3];
        const float h4 = (x[4] - mu) * rstd * ln1_g[4] + ln1_b[4];
        const float h5 = (x[5] - mu) * rstd * ln1_g[5] + ln1_b[5];
        #pragma unroll
        for (int r = 0; r < 6; ++r)
            q[r] = h3 * q_w[r * 3 + 0] + h4 * q_w[r * 3 + 1] + h5 * q_w[r * 3 + 2];
    }
    const v2f Q03 = {q[0], q[3]}, Q14 = {q[1], q[4]}, Q25 = {q[2], q[5]};

    // ---------------- causal attention: exact trip count, zero divergence ----------------
    v2f L = {0.f, 0.f}, A0 = {0.f, 0.f}, A1 = {0.f, 0.f}, A2 = {0.f, 0.f};
    int ids48 = (int)ids16[lane];
    const char* kp = (const char*)kvs;
    for (int s = 0; s <= t; ++s) {
        const v4f* e4 = (const v4f*)(kp + ids48);
        const v4f ka = e4[0], kb = e4[1], vb = e4[2];
        ids48 = (int)ids16[(s + 1) * 64 + lane];   // padded row 34 makes s==t safe
        v2f sc = fma2(Q03, SV2(ka, 0, 1),
                 fma2(Q14, SV2(ka, 2, 3),
                      Q25 * SV2(kb, 0, 1)));
        v2f p; p.x = EXP2F(sc.x); p.y = EXP2F(sc.y);
        L += p;
        A0 = fma2(p, SV2(kb, 2, 3), A0);
        A1 = fma2(p, SV2(vb, 0, 1), A1);
        A2 = fma2(p, SV2(vb, 2, 3), A2);
        kp += VV * 48;
    }
    v2f I; I.x = RCPF(L.x); I.y = RCPF(L.y);
    const v2f O0 = A0 * I, O1 = A1 * I, O2 = A2 * I;
    const float o6[6] = {O0.x, O1.x, O2.x, O0.y, O1.y, O2.y};

    // ---------------- residual + out proj (packed over d-pairs) ----------------
    v2f X0 = {x[0], x[1]}, X1 = {x[2], x[3]}, X2 = {x[4], x[5]};
    #pragma unroll
    for (int j = 0; j < 6; ++j) {
        const v2f oj = bc2(o6[j]);
        X0 = fma2(oj, LD2(j * 6 + 0), X0);
        X1 = fma2(oj, LD2(j * 6 + 2), X1);
        X2 = fma2(oj, LD2(j * 6 + 4), X2);
    }

    // ---------------- LN2 + FFN (exact gelu) + residual, packed ----------------
    {
        v2f S = X0 + X1 + X2;
        const float mu = (S.x + S.y) * (1.0f / 6.0f);
        const v2f muv = bc2(mu);
        const v2f D0 = X0 - muv, D1 = X1 - muv, D2 = X2 - muv;
        v2f E = fma2(D0, D0, fma2(D1, D1, D2 * D2));
        const float rstd = rsqrtf((E.x + E.y) * (1.0f / 6.0f) + 1e-5f);
        const v2f rs = bc2(rstd);
        const v2f H0 = fma2(D0 * rs, LD2(36), LD2(42));
        const v2f H1 = fma2(D1 * rs, LD2(38), LD2(44));
        const v2f H2 = fma2(D2 * rs, LD2(40), LD2(46));
        const float h[6] = {H0.x, H0.y, H1.x, H1.y, H2.x, H2.y};
        v2f F = LD2(66);
        float f2 = wsm[68];
        #pragma unroll
        for (int d = 0; d < 6; ++d) {
            F  = fma2(bc2(h[d]), LD2(48 + 2 * d), F);
            f2 = fmaf(h[d], wsm[60 + d], f2);
        }
        float g3[3];
        g3[0] = 0.5f * F.x * (1.0f + erff(F.x * 0.70710678118654752f));
        g3[1] = 0.5f * F.y * (1.0f + erff(F.y * 0.70710678118654752f));
        g3[2] = 0.5f * f2  * (1.0f + erff(f2  * 0.70710678118654752f));
        X0 += LD2(88); X1 += LD2(90); X2 += LD2(92);
        #pragma unroll
        for (int i = 0; i < 3; ++i) {
            const v2f gi = bc2(g3[i]);
            X0 = fma2(gi, LD2(70 + i * 6 + 0), X0);
            X1 = fma2(gi, LD2(70 + i * 6 + 2), X1);
            X2 = fma2(gi, LD2(70 + i * 6 + 4), X2);
        }
    }

    // ---------------- LNF folded into rank-3 head, packed ----------------
    v2f lgv[7];
    {
        v2f S = X0 + X1 + X2;
        const float mu = (S.x + S.y) * (1.0f / 6.0f);
        const v2f muv = bc2(mu);
        const v2f D0 = X0 - muv, D1 = X1 - muv, D2 = X2 - muv;
        v2f E = fma2(D0, D0, fma2(D1, D1, D2 * D2));
        const float rstd = rsqrtf((E.x + E.y) * (1.0f / 6.0f) + 1e-5f);
        const float xd[6] = {D0.x, D0.y, D1.x, D1.y, D2.x, D2.y};
        v2f D01 = {0.f, 0.f};
        float d2 = 0.f;
        #pragma unroll
        for (int d = 0; d < 6; ++d) {
            D01 = fma2(bc2(xd[d]), LD2(96 + 2 * d), D01);
            d2  = fmaf(xd[d], wsm[108 + d], d2);
        }
        const v2f y01 = fma2(bc2(rstd), D01, LD2(118));
        const float y2 = fmaf(rstd, d2, wsm[120]);
        const v2f Y0 = bc2(y01.x), Y1 = bc2(y01.y), Y2 = bc2(y2);
        #pragma unroll
        for (int mm = 0; mm < 7; ++mm)
            lgv[mm] = fma2(Y0, LD2(122 + 2 * mm),
                      fma2(Y1, LD2(136 + 2 * mm),
                           Y2 * LD2(150 + 2 * mm)));
    }

    // ---------------- direct store: 14 floats, alignment by element parity ----------------
    const int eidx = b * TT + t;
    float* __restrict__ outp = out + (size_t)eidx * VV;
    if (!(eidx & 1)) {   // 16B-aligned base
        v4f w0; w0.x = lgv[0].x; w0.y = lgv[0].y; w0.z = lgv[1].x; w0.w = lgv[1].y;
        v4f w1; w1.x = lgv[2].x; w1.y = lgv[2].y; w1.z = lgv[3].x; w1.w = lgv[3].y;
        v4f w2; w2.x = lgv[4].x; w2.y = lgv[4].y; w2.z = lgv[5].x; w2.w = lgv[5].y;
        *reinterpret_cast<v4f*>(outp + 0) = w0;
        *reinterpret_cast<v4f*>(outp + 4) = w1;
        *reinterpret_cast<v4f*>(outp + 8) = w2;
        *reinterpret_cast<v2f*>(outp + 12) = lgv[6];
    } else {             // 8B-aligned base
        *reinterpret_cast<v2f*>(outp + 0) = lgv[0];
        v4f w0; w0.x = lgv[1].x; w0.y = lgv[1].y; w0.z = lgv[2].x; w0.w = lgv[2].y;
        v4f w1; w1.x = lgv[3].x; w1.y = lgv[3].y; w1.z = lgv[4].x; w1.w = lgv[4].y;
        v4f w2; w2.x = lgv[5].x; w2.y = lgv[5].y; w2.z = lgv[6].x; w2.w = lgv[6].y;
        *reinterpret_cast<v4f*>(outp + 2)  = w0;
        *reinterpret_cast<v4f*>(outp + 6)  = w1;
        *reinterpret_cast<v4f*>(outp + 10) = w2;
    }
}

extern "C" void kernel_launch(void* const* d_in, const int* in_sizes, int n_in,
                              void* d_out, int out_size, void* d_ws, size_t ws_size,
                              hipStream_t stream) {
    const int*   idx     = (const int*)  d_in[0];
    const float* tok_emb = (const float*)d_in[1];
    const float* pos_enc = (const float*)d_in[2];
    const float* q_w     = (const float*)d_in[3];
    const float* k_w     = (const float*)d_in[4];
    const float* v_w     = (const float*)d_in[5];
    const float* out_w   = (const float*)d_in[6];
    const float* ln1_g   = (const float*)d_in[7];
    const float* ln1_b   = (const float*)d_in[8];
    const float* ln2_g   = (const float*)d_in[9];
    const float* ln2_b   = (const float*)d_in[10];
    const float* lnf_g   = (const float*)d_in[11];
    const float* lnf_b   = (const float*)d_in[12];
    const float* ffn_w1  = (const float*)d_in[13];
    const float* ffn_b1  = (const float*)d_in[14];
    const float* ffn_w2  = (const float*)d_in[15];
    const float* ffn_b2  = (const float*)d_in[16];
    const float* head_w  = (const float*)d_in[17];
    float* out = (float*)d_out;

    const int n      = in_sizes[0];      // B*T = 65536*34
    const int seqs   = n / TT;           // 65536
    const int chunks = seqs / 64;        // 1024
    const int blocks = chunks * 5;       // 5120 (4x 8-t chunks + 1x 2-t chunk)
    addtx_fwd<<<blocks, BLK, 0, stream>>>(idx, tok_emb, pos_enc, q_w, k_w, v_w, out_w,
                                          ln1_g, ln1_b, ln2_g, ln2_b, lnf_g, lnf_b,
                                          ffn_w1, ffn_b1, ffn_w2, ffn_b2, head_w, out);
}

// Round 11
// 216.308 us; speedup vs baseline: 1.1216x; 1.1216x over previous
//
#include <hip/hip_runtime.h>
#include <math.h>

#define TT  34   // seq len
#define VV  14   // vocab
#define BLK 512  // threads per block (8 waves), one element per thread

typedef float v2f __attribute__((ext_vector_type(2)));
typedef float v4f __attribute__((ext_vector_type(4)));

#if __has_builtin(__builtin_amdgcn_exp2f)
#define EXP2F(x) __builtin_amdgcn_exp2f(x)
#else
#define EXP2F(x) exp2f(x)
#endif
#if __has_builtin(__builtin_amdgcn_rcpf)
#define RCPF(x) __builtin_amdgcn_rcpf(x)
#else
#define RCPF(x) (1.0f/(x))
#endif

static __device__ __forceinline__ v2f fma2(v2f a, v2f b, v2f c) {
    return __builtin_elementwise_fma(a, b, c);   // -> v_pk_fma_f32 on gfx950
}
static __device__ __forceinline__ v2f bc2(float s) { v2f r; r.x = s; r.y = s; return r; }
#define SV2(v, a, b) __builtin_shufflevector((v), (v), (a), (b))
#define LD2(i) (*reinterpret_cast<const v2f*>(&wsm[(i)]))

// wsm layout (floats), all v2f read-bases even (8B-aligned):
//   0..35   owT[j*6+d]   = out_w[d*6+j]
//  36..41   ln2_g        42..47 ln2_b
//  48..59   w1p[d*2+i]   = ffn_w1[i*6+d], i in {0,1}
//  60..65   w1r[d]       = ffn_w1[12+d]
//  66..68   ffn_b1       69 pad
//  70..87   w2T[i*6+d]   = ffn_w2[d*3+i]
//  88..93   ffn_b2       94..95 pad
//  96..107  Gp[d*2+c]    = lnf_g[d]*head_w[c*6+d], c in {0,1}
// 108..113  G2[d]        = lnf_g[d]*head_w[12+d]
// 114..117  pad
// 118..120  eC[c]        = sum_d lnf_b[d]*head_w[c*6+d]
// 121      pad
// 122..163  MT[c*14+v]   = tok_emb[v*3+c]   (fused head rows)
// 164..205  tok_emb natural [v*3+c]
// 206..307  pos_enc natural [t*3+c]

// __launch_bounds__ 2nd arg decoded this session as MIN-BLOCKS-PER-CU:
// (512,8)->cap 32, (512,6)->cap 40, (512,3)->cap ~85. (512,4) -> 8 waves/SIMD
// -> cap 64 VGPR while keeping the 32-wave/CU ceiling (LDS 26.5KB allows 4 blocks).
__global__ __launch_bounds__(BLK, 4) void addtx_fwd(
    const int*   __restrict__ idx,
    const float* __restrict__ tok_emb,
    const float* __restrict__ pos_enc,
    const float* __restrict__ q_w,
    const float* __restrict__ k_w,
    const float* __restrict__ v_w,
    const float* __restrict__ out_w,
    const float* __restrict__ ln1_g, const float* __restrict__ ln1_b,
    const float* __restrict__ ln2_g, const float* __restrict__ ln2_b,
    const float* __restrict__ lnf_g, const float* __restrict__ lnf_b,
    const float* __restrict__ ffn_w1, const float* __restrict__ ffn_b1,
    const float* __restrict__ ffn_w2, const float* __restrict__ ffn_b2,
    const float* __restrict__ head_w,
    float* __restrict__ out, int n)
{
    // kv entry e=(pos,tok), pair-interleaved, k pre-scaled 1/sqrt(3)*log2e:
    //  f4[0]=(k0,k3,k1,k4)  f4[1]=(k2,k5,v0,v3)  f4[2]=(v1,v4,v2,v5)
    __shared__ v4f   kvs[TT * VV * 3];   // 22848 B
    __shared__ float wsm[308];           //  1232 B
    __shared__ int   idsb[594];          //  2376 B  (linear staging: conflict-free)

    const int tid = threadIdx.x;
    const int blk = blockIdx.x;

    // ---------------- stage weights (transposed / pair-interleaved) ----------------
    if (tid < 308) {
        const int i = tid;
        float val = 0.0f;
        if (i < 36)       { const int j = i / 6, d = i - j * 6; val = out_w[d * 6 + j]; }
        else if (i < 42)  val = ln2_g[i - 36];
        else if (i < 48)  val = ln2_b[i - 42];
        else if (i < 60)  { const int k = i - 48, d = k >> 1, ii = k & 1; val = ffn_w1[ii * 6 + d]; }
        else if (i < 66)  val = ffn_w1[12 + (i - 60)];
        else if (i < 69)  val = ffn_b1[i - 66];
        else if (i < 70)  val = 0.0f;
        else if (i < 88)  { const int k = i - 70, ii = k / 6, d = k - ii * 6; val = ffn_w2[d * 3 + ii]; }
        else if (i < 94)  val = ffn_b2[i - 88];
        else if (i < 96)  val = 0.0f;
        else if (i < 108) { const int k = i - 96, d = k >> 1, c = k & 1; val = lnf_g[d] * head_w[c * 6 + d]; }
        else if (i < 114) { const int d = i - 108; val = lnf_g[d] * head_w[12 + d]; }
        else if (i < 118) val = 0.0f;
        else if (i < 121) { const int c = i - 118; float s = 0.0f;
                            #pragma unroll
                            for (int d = 0; d < 6; ++d) s += lnf_b[d] * head_w[c * 6 + d];
                            val = s; }
        else if (i < 122) val = 0.0f;
        else if (i < 164) { const int k = i - 122, c = k / 14, v = k - c * 14; val = tok_emb[v * 3 + c]; }
        else if (i < 206) val = tok_emb[i - 164];
        else              val = pos_enc[i - 206];
        wsm[i] = val;
    }

    // ---------------- stage this block's token ids (coalesced), pre-scaled *48 ----------------
    const int p0 = blk * BLK;            // first global element index
    const int b0 = p0 / TT;              // first sequence
    {
        const int gb = b0 * TT;
        for (int e = tid; e < 594; e += BLK) {
            const int g = gb + e;
            idsb[e] = (g < n) ? (idx[g] * 48) : 0;
        }
    }

    // ---------------- build (pos,tok) -> k,v table ----------------
    const float rs3l = 0.57735026918962576f * 1.4426950408889634f; // 1/sqrt(3)*log2e
    for (int e = tid; e < TT * VV; e += BLK) {
        const int pos = e / VV, id = e - pos * VV;
        float x[6];
        x[0] = tok_emb[id * 3 + 0]; x[1] = tok_emb[id * 3 + 1]; x[2] = tok_emb[id * 3 + 2];
        x[3] = pos_enc[pos * 3 + 0]; x[4] = pos_enc[pos * 3 + 1]; x[5] = pos_enc[pos * 3 + 2];
        float mu = (x[0] + x[1] + x[2] + x[3] + x[4] + x[5]) * (1.0f / 6.0f);
        float var = 0.0f;
        #pragma unroll
        for (int d = 0; d < 6; ++d) { float dd = x[d] - mu; var += dd * dd; }
        const float rstd = rsqrtf(var * (1.0f / 6.0f) + 1e-5f);
        float h[6];
        #pragma unroll
        for (int d = 0; d < 6; ++d) h[d] = (x[d] - mu) * rstd * ln1_g[d] + ln1_b[d];
        float kk[6], vvv[6];
        #pragma unroll
        for (int r = 0; r < 6; ++r) {
            kk[r]  = (h[3] * k_w[r * 3 + 0] + h[4] * k_w[r * 3 + 1] + h[5] * k_w[r * 3 + 2]) * rs3l;
            vvv[r] =  h[0] * v_w[r * 3 + 0] + h[1] * v_w[r * 3 + 1] + h[2] * v_w[r * 3 + 2];
        }
        v4f f0; f0.x = kk[0]; f0.y = kk[3]; f0.z = kk[1]; f0.w = kk[4];
        v4f f1; f1.x = kk[2]; f1.y = kk[5]; f1.z = vvv[0]; f1.w = vvv[3];
        v4f f2; f2.x = vvv[1]; f2.y = vvv[4]; f2.z = vvv[2]; f2.w = vvv[5];
        kvs[e * 3 + 0] = f0;
        kvs[e * 3 + 1] = f1;
        kvs[e * 3 + 2] = f2;
    }
    __syncthreads();     // the ONLY barrier; waves retire independently afterwards

    // ---------------- t-balanced intra-block remap (closed form, BLK=512, r5-verified) ----------------
    const int srank = (tid + ((blk & 7) << 6)) & (BLK - 1);
    const int r0 = p0 % TT;
    const int thrA = 15 * r0;
    int t, dlt, ksel;
    if (srank < thrA)           { t = srank / 15; ksel = srank - 15 * t; dlt = t - r0 + TT; }
    else if (srank < thrA + 32) { const int rr = srank - thrA; dlt = rr >> 4; ksel = rr & 15; t = r0 + dlt; }
    else                        { const int rr = srank - thrA - 32; const int qq = rr / 15;
                                  ksel = rr - 15 * qq; dlt = 2 + qq; t = r0 + dlt; }
    const int il   = dlt + TT * ksel;    // local slot in [0,512), bijection of tid
    const int flat = p0 + il;
    const int b    = flat / TT;          // flat % TT == t by construction
    const int* __restrict__ rowL = idsb + (b - b0) * TT;   // LDS-resident, values = id*48

    // ---------------- own x (pre-LN residual) and q ----------------
    float x[6];
    {
        const int tb = rowL[t] >> 4;   // id*3
        x[0] = wsm[164 + tb]; x[1] = wsm[165 + tb]; x[2] = wsm[166 + tb];
        x[3] = wsm[206 + t * 3]; x[4] = wsm[207 + t * 3]; x[5] = wsm[208 + t * 3];
    }
    float q[6];
    {
        float mu = (x[0] + x[1] + x[2] + x[3] + x[4] + x[5]) * (1.0f / 6.0f);
        float var = 0.0f;
        #pragma unroll
        for (int d = 0; d < 6; ++d) { float dd = x[d] - mu; var += dd * dd; }
        const float rstd = rsqrtf(var * (1.0f / 6.0f) + 1e-5f);
        const float h3 = (x[3] - mu) * rstd * ln1_g[3] + ln1_b[3];
        const float h4 = (x[4] - mu) * rstd * ln1_g[4] + ln1_b[4];
        const float h5 = (x[5] - mu) * rstd * ln1_g[5] + ln1_b[5];
        #pragma unroll
        for (int r = 0; r < 6; ++r)
            q[r] = h3 * q_w[r * 3 + 0] + h4 * q_w[r * 3 + 1] + h5 * q_w[r * 3 + 2];
    }
    const v2f Q03 = {q[0], q[3]}, Q14 = {q[1], q[4]}, Q25 = {q[2], q[5]};

    // ---------------- causal attention, unrolled x2 (6 ds_reads in flight per pair) ----------------
    v2f L = {0.f, 0.f}, A0 = {0.f, 0.f}, A1 = {0.f, 0.f}, A2 = {0.f, 0.f};
    const char* kp = (const char*)kvs;
    int ids_a = rowL[0];
    int s = 0;
    for (; s + 1 <= t; s += 2) {
        const int ids_b = rowL[s + 1];
        const v4f* ea = (const v4f*)(kp + ids_a);
        const v4f* eb = (const v4f*)(kp + (VV * 48) + ids_b);
        const v4f ka0 = ea[0], kb0 = ea[1], vb0 = ea[2];
        const v4f ka1 = eb[0], kb1 = eb[1], vb1 = eb[2];
        ids_a = rowL[s + 2];                 // bounded by rowL[34] (padded to 594)
        v2f sc0 = fma2(Q03, SV2(ka0, 0, 1), fma2(Q14, SV2(ka0, 2, 3), Q25 * SV2(kb0, 0, 1)));
        v2f sc1 = fma2(Q03, SV2(ka1, 0, 1), fma2(Q14, SV2(ka1, 2, 3), Q25 * SV2(kb1, 0, 1)));
        v2f pp0; pp0.x = EXP2F(sc0.x); pp0.y = EXP2F(sc0.y);
        v2f pp1; pp1.x = EXP2F(sc1.x); pp1.y = EXP2F(sc1.y);
        L += pp0; L += pp1;
        A0 = fma2(pp0, SV2(kb0, 2, 3), A0); A1 = fma2(pp0, SV2(vb0, 0, 1), A1); A2 = fma2(pp0, SV2(vb0, 2, 3), A2);
        A0 = fma2(pp1, SV2(kb1, 2, 3), A0); A1 = fma2(pp1, SV2(vb1, 0, 1), A1); A2 = fma2(pp1, SV2(vb1, 2, 3), A2);
        kp += 2 * VV * 48;
    }
    if (s <= t) {   // tail (odd trip count: t even)
        const v4f* ea = (const v4f*)(kp + ids_a);
        const v4f ka = ea[0], kb = ea[1], vb = ea[2];
        v2f sc = fma2(Q03, SV2(ka, 0, 1), fma2(Q14, SV2(ka, 2, 3), Q25 * SV2(kb, 0, 1)));
        v2f pp; pp.x = EXP2F(sc.x); pp.y = EXP2F(sc.y);
        L += pp;
        A0 = fma2(pp, SV2(kb, 2, 3), A0);
        A1 = fma2(pp, SV2(vb, 0, 1), A1);
        A2 = fma2(pp, SV2(vb, 2, 3), A2);
    }
    v2f I; I.x = RCPF(L.x); I.y = RCPF(L.y);
    const v2f O0 = A0 * I, O1 = A1 * I, O2 = A2 * I;
    const float o6[6] = {O0.x, O1.x, O2.x, O0.y, O1.y, O2.y};

    // ---------------- residual + out proj (packed over d-pairs) ----------------
    v2f X0 = {x[0], x[1]}, X1 = {x[2], x[3]}, X2 = {x[4], x[5]};
    #pragma unroll
    for (int j = 0; j < 6; ++j) {
        const v2f oj = bc2(o6[j]);
        X0 = fma2(oj, LD2(j * 6 + 0), X0);
        X1 = fma2(oj, LD2(j * 6 + 2), X1);
        X2 = fma2(oj, LD2(j * 6 + 4), X2);
    }

    // ---------------- LN2 + FFN (exact gelu) + residual, packed ----------------
    {
        v2f S = X0 + X1 + X2;
        const float mu = (S.x + S.y) * (1.0f / 6.0f);
        const v2f muv = bc2(mu);
        const v2f D0 = X0 - muv, D1 = X1 - muv, D2 = X2 - muv;
        v2f E = fma2(D0, D0, fma2(D1, D1, D2 * D2));
        const float rstd = rsqrtf((E.x + E.y) * (1.0f / 6.0f) + 1e-5f);
        const v2f rs = bc2(rstd);
        const v2f H0 = fma2(D0 * rs, LD2(36), LD2(42));
        const v2f H1 = fma2(D1 * rs, LD2(38), LD2(44));
        const v2f H2 = fma2(D2 * rs, LD2(40), LD2(46));
        const float h[6] = {H0.x, H0.y, H1.x, H1.y, H2.x, H2.y};
        v2f F = LD2(66);
        float f2 = wsm[68];
        #pragma unroll
        for (int d = 0; d < 6; ++d) {
            F  = fma2(bc2(h[d]), LD2(48 + 2 * d), F);
            f2 = fmaf(h[d], wsm[60 + d], f2);
        }
        float g3[3];
        g3[0] = 0.5f * F.x * (1.0f + erff(F.x * 0.70710678118654752f));
        g3[1] = 0.5f * F.y * (1.0f + erff(F.y * 0.70710678118654752f));
        g3[2] = 0.5f * f2  * (1.0f + erff(f2  * 0.70710678118654752f));
        X0 += LD2(88); X1 += LD2(90); X2 += LD2(92);
        #pragma unroll
        for (int i = 0; i < 3; ++i) {
            const v2f gi = bc2(g3[i]);
            X0 = fma2(gi, LD2(70 + i * 6 + 0), X0);
            X1 = fma2(gi, LD2(70 + i * 6 + 2), X1);
            X2 = fma2(gi, LD2(70 + i * 6 + 4), X2);
        }
    }

    // ---------------- LNF folded into rank-3 head, packed ----------------
    v2f lgv[7];
    {
        v2f S = X0 + X1 + X2;
        const float mu = (S.x + S.y) * (1.0f / 6.0f);
        const v2f muv = bc2(mu);
        const v2f D0 = X0 - muv, D1 = X1 - muv, D2 = X2 - muv;
        v2f E = fma2(D0, D0, fma2(D1, D1, D2 * D2));
        const float rstd = rsqrtf((E.x + E.y) * (1.0f / 6.0f) + 1e-5f);
        const float xd[6] = {D0.x, D0.y, D1.x, D1.y, D2.x, D2.y};
        v2f D01 = {0.f, 0.f};
        float d2 = 0.f;
        #pragma unroll
        for (int d = 0; d < 6; ++d) {
            D01 = fma2(bc2(xd[d]), LD2(96 + 2 * d), D01);
            d2  = fmaf(xd[d], wsm[108 + d], d2);
        }
        const v2f y01 = fma2(bc2(rstd), D01, LD2(118));
        const float y2 = fmaf(rstd, d2, wsm[120]);
        const v2f Y0 = bc2(y01.x), Y1 = bc2(y01.y), Y2 = bc2(y2);
        #pragma unroll
        for (int mm = 0; mm < 7; ++mm)
            lgv[mm] = fma2(Y0, LD2(122 + 2 * mm),
                      fma2(Y1, LD2(136 + 2 * mm),
                           Y2 * LD2(150 + 2 * mm)));
    }

    // ---------------- direct store: 14 floats, alignment by element parity ----------------
    float* __restrict__ outp = out + (size_t)flat * VV;
    if (!(flat & 1)) {   // 16B-aligned base
        v4f w0; w0.x = lgv[0].x; w0.y = lgv[0].y; w0.z = lgv[1].x; w0.w = lgv[1].y;
        v4f w1; w1.x = lgv[2].x; w1.y = lgv[2].y; w1.z = lgv[3].x; w1.w = lgv[3].y;
        v4f w2; w2.x = lgv[4].x; w2.y = lgv[4].y; w2.z = lgv[5].x; w2.w = lgv[5].y;
        *reinterpret_cast<v4f*>(outp + 0) = w0;
        *reinterpret_cast<v4f*>(outp + 4) = w1;
        *reinterpret_cast<v4f*>(outp + 8) = w2;
        *reinterpret_cast<v2f*>(outp + 12) = lgv[6];
    } else {             // 8B-aligned base
        *reinterpret_cast<v2f*>(outp + 0) = lgv[0];
        v4f w0; w0.x = lgv[1].x; w0.y = lgv[1].y; w0.z = lgv[2].x; w0.w = lgv[2].y;
        v4f w1; w1.x = lgv[3].x; w1.y = lgv[3].y; w1.z = lgv[4].x; w1.w = lgv[4].y;
        v4f w2; w2.x = lgv[5].x; w2.y = lgv[5].y; w2.z = lgv[6].x; w2.w = lgv[6].y;
        *reinterpret_cast<v4f*>(outp + 2)  = w0;
        *reinterpret_cast<v4f*>(outp + 6)  = w1;
        *reinterpret_cast<v4f*>(outp + 10) = w2;
    }
}

extern "C" void kernel_launch(void* const* d_in, const int* in_sizes, int n_in,
                              void* d_out, int out_size, void* d_ws, size_t ws_size,
                              hipStream_t stream) {
    const int*   idx     = (const int*)  d_in[0];
    const float* tok_emb = (const float*)d_in[1];
    const float* pos_enc = (const float*)d_in[2];
    const float* q_w     = (const float*)d_in[3];
    const float* k_w     = (const float*)d_in[4];
    const float* v_w     = (const float*)d_in[5];
    const float* out_w   = (const float*)d_in[6];
    const float* ln1_g   = (const float*)d_in[7];
    const float* ln1_b   = (const float*)d_in[8];
    const float* ln2_g   = (const float*)d_in[9];
    const float* ln2_b   = (const float*)d_in[10];
    const float* lnf_g   = (const float*)d_in[11];
    const float* lnf_b   = (const float*)d_in[12];
    const float* ffn_w1  = (const float*)d_in[13];
    const float* ffn_b1  = (const float*)d_in[14];
    const float* ffn_w2  = (const float*)d_in[15];
    const float* ffn_b2  = (const float*)d_in[16];
    const float* head_w  = (const float*)d_in[17];
    float* out = (float*)d_out;

    const int n = in_sizes[0];        // B*T = 65536*34 = 2228224, divisible by 512
    const int blocks = n / BLK;       // 4352
    addtx_fwd<<<blocks, BLK, 0, stream>>>(idx, tok_emb, pos_enc, q_w, k_w, v_w, out_w,
                                          ln1_g, ln1_b, ln2_g, ln2_b, lnf_g, lnf_b,
                                          ffn_w1, ffn_b1, ffn_w2, ffn_b2, head_w, out, n);
}